// Round 1
// baseline (504.668 us; speedup 1.0000x reference)
//
#include <hip/hip_runtime.h>
#include <cstdint>
#include <cstddef>

typedef __bf16 bf16;
typedef __bf16 bf16x8 __attribute__((ext_vector_type(8)));
typedef float f32x4 __attribute__((ext_vector_type(4)));
typedef uint32_t u32x4 __attribute__((ext_vector_type(4)));

#define S_LEN 2048
#define BATCH 2
#define DM 1024
#define NH 16
#define DKH 64
#define MTOT (S_LEN * BATCH)  // 4096

// ---------------- fp32 -> bf16 convert (8 elems/thread) ----------------
__global__ __launch_bounds__(256) void convert_kernel(const float* __restrict__ src,
                                                      bf16* __restrict__ dst, int n8) {
    int i = blockIdx.x * 256 + threadIdx.x;
    if (i >= n8) return;
    const float4* s4 = (const float4*)src;
    float4 a = s4[2 * i];
    float4 b = s4[2 * i + 1];
    bf16x8 v;
    v[0] = (bf16)a.x; v[1] = (bf16)a.y; v[2] = (bf16)a.z; v[3] = (bf16)a.w;
    v[4] = (bf16)b.x; v[5] = (bf16)b.y; v[6] = (bf16)b.z; v[7] = (bf16)b.w;
    *(bf16x8*)(dst + 8 * (size_t)i) = v;
}

// ---------------- GEMM: C = A(M,K) @ Bt(N,K)^T + bias ----------------
// tile 128x128, BK=32, 4 waves in 2x2, each wave 64x64 (4x4 MFMA tiles).
// mode 0: store bf16 row-major (M,N)
// mode 1: store bf16 V^T layout (B,H,DK,S):  [((b*NH+h)*DKH+dk)*S + s]
// mode 2: store fp32 row-major (M,N)   (final output)
__global__ __launch_bounds__(256) void gemm_bt(const bf16* __restrict__ A,
                                               const bf16* __restrict__ Bt,
                                               const float* __restrict__ bias,
                                               void* __restrict__ out, int mode) {
    __shared__ bf16 As[128 * 32];
    __shared__ bf16 Bs[128 * 32];
    const int K = DM;
    int t = threadIdx.x;
    int lane = t & 63, wave = t >> 6;
    int lm = lane & 15, quad = lane >> 4;
    int m0 = blockIdx.y * 128, n0 = blockIdx.x * 128;
    int wm = (wave >> 1) * 64, wn = (wave & 1) * 64;
    f32x4 acc[4][4] = {};
    int seg0 = t, seg1 = t + 256;
    int row0 = seg0 >> 2, kq0 = (seg0 & 3) * 8;
    int row1 = seg1 >> 2, kq1 = (seg1 & 3) * 8;
    for (int k0 = 0; k0 < K; k0 += 32) {
        u32x4 a0 = *(const u32x4*)(A + (size_t)(m0 + row0) * K + k0 + kq0);
        u32x4 a1 = *(const u32x4*)(A + (size_t)(m0 + row1) * K + k0 + kq1);
        u32x4 b0 = *(const u32x4*)(Bt + (size_t)(n0 + row0) * K + k0 + kq0);
        u32x4 b1 = *(const u32x4*)(Bt + (size_t)(n0 + row1) * K + k0 + kq1);
        *(u32x4*)(As + seg0 * 8) = a0;
        *(u32x4*)(As + seg1 * 8) = a1;
        *(u32x4*)(Bs + seg0 * 8) = b0;
        *(u32x4*)(Bs + seg1 * 8) = b1;
        __syncthreads();
        bf16x8 af[4], bfr[4];
#pragma unroll
        for (int i = 0; i < 4; ++i)
            af[i] = *(const bf16x8*)(As + (wm + i * 16 + lm) * 32 + quad * 8);
#pragma unroll
        for (int j = 0; j < 4; ++j)
            bfr[j] = *(const bf16x8*)(Bs + (wn + j * 16 + lm) * 32 + quad * 8);
#pragma unroll
        for (int i = 0; i < 4; ++i)
#pragma unroll
            for (int j = 0; j < 4; ++j)
                acc[i][j] = __builtin_amdgcn_mfma_f32_16x16x32_bf16(af[i], bfr[j], acc[i][j], 0, 0, 0);
        __syncthreads();
    }
#pragma unroll
    for (int i = 0; i < 4; ++i) {
#pragma unroll
        for (int j = 0; j < 4; ++j) {
            int col = n0 + wn + j * 16 + lm;
            float bv = bias[col];
            f32x4 v = acc[i][j];
#pragma unroll
            for (int r = 0; r < 4; ++r) {
                int row = m0 + wm + i * 16 + quad * 4 + r;
                float val = v[r] + bv;
                if (mode == 0) {
                    ((bf16*)out)[(size_t)row * DM + col] = (bf16)val;
                } else if (mode == 1) {
                    int s = row >> 1, b = row & 1;
                    int h = col >> 6, dk = col & 63;
                    ((bf16*)out)[((size_t)(b * NH + h) * DKH + dk) * S_LEN + s] = (bf16)val;
                } else {
                    ((float*)out)[(size_t)row * DM + col] = val;
                }
            }
        }
    }
}

// ---------------- RoPE in-place on q and k (row-major (S,B,D) bf16) ----------------
// Folds 0.125 * log2(e) into q so flash softmax runs in exp2 space.
__global__ __launch_bounds__(256) void rope_kernel(bf16* __restrict__ q, bf16* __restrict__ k,
                                                   const float* __restrict__ qc, const float* __restrict__ qs,
                                                   const float* __restrict__ kc, const float* __restrict__ ks) {
    int i = blockIdx.x * 256 + threadIdx.x;  // S*B*NH*32 threads
    int dk = i & 31;
    int h = (i >> 5) & 15;
    int b = (i >> 9) & 1;
    int s = i >> 10;
    size_t base = ((size_t)s * BATCH + b) * DM + h * DKH;
    int ti = s * DKH + dk;
    const float qscale = 0.125f * 1.44269504088896f;
    float c1 = qc[ti], s1 = qs[ti], c2 = qc[ti + 32], s2 = qs[ti + 32];
    float x1 = (float)q[base + dk], x2 = (float)q[base + dk + 32];
    q[base + dk]      = (bf16)((x1 * c1 - x2 * s1) * qscale);
    q[base + dk + 32] = (bf16)((x2 * c2 + x1 * s2) * qscale);
    float kc1 = kc[ti], ks1 = ks[ti], kc2 = kc[ti + 32], ks2 = ks[ti + 32];
    float y1 = (float)k[base + dk], y2 = (float)k[base + dk + 32];
    k[base + dk]      = (bf16)(y1 * kc1 - y2 * ks1);
    k[base + dk + 32] = (bf16)(y2 * kc2 + y1 * ks2);
}

// ---------------- Flash attention (causal), BQ=64/block, 16 q-rows/wave ----------------
// q,k: row-major (S,B,D) bf16 (post-rope; q pre-scaled).  vT: (B,H,DK,S) bf16.
// ctx out: row-major (S,B,D) bf16.
__global__ __launch_bounds__(256) void flash_kernel(const bf16* __restrict__ qp, const bf16* __restrict__ kp,
                                                    const bf16* __restrict__ vT, bf16* __restrict__ ctx) {
    int qt = blockIdx.x;
    int bh = blockIdx.y;
    int b = bh >> 4, h = bh & 15;
    int t = threadIdx.x, lane = t & 63, wave = t >> 6;
    int lm = lane & 15, quad = lane >> 4;
    __shared__ bf16 pbuf[4][16 * 64];
    bf16* myp = &pbuf[wave][0];
    int qrow0 = qt * 64 + wave * 16;
    int qg = qrow0 + lm;
    const bf16* qrow = qp + ((size_t)qg * BATCH + b) * DM + h * DKH;
    bf16x8 aq0 = *(const bf16x8*)(qrow + quad * 8);
    bf16x8 aq1 = *(const bf16x8*)(qrow + 32 + quad * 8);
    f32x4 o[4] = {};
    float m_i[4] = {-1e30f, -1e30f, -1e30f, -1e30f};
    float l_i[4] = {0.f, 0.f, 0.f, 0.f};
    int kvmax = qrow0 + 15;  // wave-local causal bound
    for (int kv0 = 0; kv0 <= kvmax; kv0 += 64) {
        f32x4 sc[4] = {};
#pragma unroll
        for (int nt = 0; nt < 4; ++nt) {
            int kvg = kv0 + nt * 16 + lm;
            const bf16* krow = kp + ((size_t)kvg * BATCH + b) * DM + h * DKH;
            bf16x8 bk0 = *(const bf16x8*)(krow + quad * 8);
            bf16x8 bk1 = *(const bf16x8*)(krow + 32 + quad * 8);
            sc[nt] = __builtin_amdgcn_mfma_f32_16x16x32_bf16(aq0, bk0, sc[nt], 0, 0, 0);
            sc[nt] = __builtin_amdgcn_mfma_f32_16x16x32_bf16(aq1, bk1, sc[nt], 0, 0, 0);
        }
        // causal mask: C-layout row = quad*4+r, col = nt*16+lm
#pragma unroll
        for (int nt = 0; nt < 4; ++nt) {
            int kvg = kv0 + nt * 16 + lm;
#pragma unroll
            for (int r = 0; r < 4; ++r)
                if (kvg > qrow0 + quad * 4 + r) sc[nt][r] = -1e30f;
        }
        // online softmax in exp2 space (scores already scaled by 0.125*log2e via q)
#pragma unroll
        for (int r = 0; r < 4; ++r) {
            float mx = fmaxf(fmaxf(sc[0][r], sc[1][r]), fmaxf(sc[2][r], sc[3][r]));
            mx = fmaxf(mx, __shfl_xor(mx, 1, 64));
            mx = fmaxf(mx, __shfl_xor(mx, 2, 64));
            mx = fmaxf(mx, __shfl_xor(mx, 4, 64));
            mx = fmaxf(mx, __shfl_xor(mx, 8, 64));
            float mn = fmaxf(m_i[r], mx);
            float al = exp2f(m_i[r] - mn);
            m_i[r] = mn;
            float rs = 0.f;
#pragma unroll
            for (int nt = 0; nt < 4; ++nt) {
                float p = exp2f(sc[nt][r] - mn);
                sc[nt][r] = p;
                rs += p;
            }
            rs += __shfl_xor(rs, 1, 64);
            rs += __shfl_xor(rs, 2, 64);
            rs += __shfl_xor(rs, 4, 64);
            rs += __shfl_xor(rs, 8, 64);
            l_i[r] = l_i[r] * al + rs;
#pragma unroll
            for (int dt = 0; dt < 4; ++dt) o[dt][r] *= al;
        }
        // P: C-layout -> row-major [16 q][64 kv] in per-wave LDS (A-layout source)
#pragma unroll
        for (int nt = 0; nt < 4; ++nt)
#pragma unroll
            for (int r = 0; r < 4; ++r)
                myp[(quad * 4 + r) * 64 + nt * 16 + lm] = (bf16)sc[nt][r];
        __builtin_amdgcn_wave_barrier();  // same-wave LDS ops are in-order; fence the compiler
        bf16x8 ap0 = *(const bf16x8*)(myp + lm * 64 + quad * 8);
        bf16x8 ap1 = *(const bf16x8*)(myp + lm * 64 + 32 + quad * 8);
#pragma unroll
        for (int dt = 0; dt < 4; ++dt) {
            const bf16* vrow = vT + ((size_t)bh * DKH + dt * 16 + lm) * S_LEN + kv0;
            bf16x8 bv0 = *(const bf16x8*)(vrow + quad * 8);
            bf16x8 bv1 = *(const bf16x8*)(vrow + 32 + quad * 8);
            o[dt] = __builtin_amdgcn_mfma_f32_16x16x32_bf16(ap0, bv0, o[dt], 0, 0, 0);
            o[dt] = __builtin_amdgcn_mfma_f32_16x16x32_bf16(ap1, bv1, o[dt], 0, 0, 0);
        }
        __builtin_amdgcn_wave_barrier();
    }
#pragma unroll
    for (int r = 0; r < 4; ++r) l_i[r] = 1.f / l_i[r];
#pragma unroll
    for (int dt = 0; dt < 4; ++dt)
#pragma unroll
        for (int r = 0; r < 4; ++r) {
            int qg2 = qrow0 + quad * 4 + r;
            ctx[((size_t)qg2 * BATCH + b) * DM + h * DKH + dt * 16 + lm] = (bf16)(o[dt][r] * l_i[r]);
        }
}

extern "C" void kernel_launch(void* const* d_in, const int* in_sizes, int n_in,
                              void* d_out, int out_size, void* d_ws, size_t ws_size,
                              hipStream_t stream) {
    const float* Q    = (const float*)d_in[0];
    const float* K    = (const float*)d_in[1];
    const float* V    = (const float*)d_in[2];
    const float* Wq   = (const float*)d_in[3];
    const float* bq   = (const float*)d_in[4];
    const float* Wk   = (const float*)d_in[5];
    const float* bk   = (const float*)d_in[6];
    const float* Wv   = (const float*)d_in[7];
    const float* bv   = (const float*)d_in[8];
    const float* Wo   = (const float*)d_in[9];
    const float* bo   = (const float*)d_in[10];
    const float* qcos = (const float*)d_in[11];
    const float* qsin = (const float*)d_in[12];
    const float* kcos = (const float*)d_in[13];
    const float* ksin = (const float*)d_in[14];
    // d_in[15] = mask: deterministic causal triu(k=1); applied analytically.

    char* ws = (char*)d_ws;
    const size_t SZ_ACT = (size_t)MTOT * DM * sizeof(bf16);  // 8 MiB
    const size_t SZ_W   = (size_t)DM * DM * sizeof(bf16);    // 2 MiB
    bf16* qb  = (bf16*)ws; ws += SZ_ACT;
    bf16* kb  = (bf16*)ws; ws += SZ_ACT;
    bf16* vb  = (bf16*)ws; ws += SZ_ACT;
    bf16* wqb = (bf16*)ws; ws += SZ_W;
    bf16* wkb = (bf16*)ws; ws += SZ_W;
    bf16* wvb = (bf16*)ws; ws += SZ_W;
    bf16* wob = (bf16*)ws; ws += SZ_W;
    bf16* qpr = (bf16*)ws; ws += SZ_ACT;
    bf16* kpr = (bf16*)ws; ws += SZ_ACT;
    bf16* vTp = (bf16*)ws; ws += SZ_ACT;
    bf16* ctx = (bf16*)ws; ws += SZ_ACT;

    const int n8_act = MTOT * DM / 8;  // 524288
    const int n8_w   = DM * DM / 8;    // 131072
    convert_kernel<<<n8_act / 256, 256, 0, stream>>>(Q, qb, n8_act);
    convert_kernel<<<n8_act / 256, 256, 0, stream>>>(K, kb, n8_act);
    convert_kernel<<<n8_act / 256, 256, 0, stream>>>(V, vb, n8_act);
    convert_kernel<<<n8_w / 256, 256, 0, stream>>>(Wq, wqb, n8_w);
    convert_kernel<<<n8_w / 256, 256, 0, stream>>>(Wk, wkb, n8_w);
    convert_kernel<<<n8_w / 256, 256, 0, stream>>>(Wv, wvb, n8_w);
    convert_kernel<<<n8_w / 256, 256, 0, stream>>>(Wo, wob, n8_w);

    dim3 g(DM / 128, MTOT / 128);  // (8, 32)
    gemm_bt<<<g, 256, 0, stream>>>(qb, wqb, bq, qpr, 0);
    gemm_bt<<<g, 256, 0, stream>>>(kb, wkb, bk, kpr, 0);
    gemm_bt<<<g, 256, 0, stream>>>(vb, wvb, bv, vTp, 1);

    rope_kernel<<<(S_LEN * BATCH * NH * 32) / 256, 256, 0, stream>>>(qpr, kpr, qcos, qsin, kcos, ksin);

    flash_kernel<<<dim3(S_LEN / 64, BATCH * NH), 256, 0, stream>>>(qpr, kpr, vTp, ctx);

    gemm_bt<<<g, 256, 0, stream>>>(ctx, wob, bo, d_out, 2);
}

// Round 2
// 301.409 us; speedup vs baseline: 1.6744x; 1.6744x over previous
//
#include <hip/hip_runtime.h>
#include <cstdint>
#include <cstddef>

typedef __bf16 bf16;
typedef __bf16 bf16x2 __attribute__((ext_vector_type(2)));
typedef __bf16 bf16x4 __attribute__((ext_vector_type(4)));
typedef __bf16 bf16x8 __attribute__((ext_vector_type(8)));
typedef float f32x4 __attribute__((ext_vector_type(4)));

#define S_LEN 2048
#define BATCH 2
#define DM 1024
#define NH 16
#define DKH 64
#define MTOT (S_LEN * BATCH)  // 4096

// async global->LDS, 16B per lane; LDS dest = wave-uniform base + lane*16
__device__ __forceinline__ void gload_lds16(const void* g, void* l) {
    __builtin_amdgcn_global_load_lds((const __attribute__((address_space(1))) uint32_t*)g,
                                     (__attribute__((address_space(3))) uint32_t*)l, 16, 0, 0);
}

__device__ __forceinline__ uint32_t pack2(float a, float b) {
    bf16x2 v; v[0] = (bf16)a; v[1] = (bf16)b;
    return __builtin_bit_cast(uint32_t, v);
}

// ---------------- fused fp32 -> bf16 convert: 3 activations (2^19 granules) + 4 weights (2^17) ----
struct ConvArgs { const float* src[7]; bf16* dst[7]; };

__global__ __launch_bounds__(256) void convert_all(ConvArgs a) {
    int gid = blockIdx.x * 256 + threadIdx.x;
    int tid, off;
    if (gid < 3 * 524288) { tid = gid >> 19; off = gid & 524287; }
    else { int r = gid - 3 * 524288; tid = 3 + (r >> 17); off = r & 131071; }
    const float4* s4 = (const float4*)a.src[tid];
    float4 x = s4[2 * off], y = s4[2 * off + 1];
    bf16x8 v;
    v[0] = (bf16)x.x; v[1] = (bf16)x.y; v[2] = (bf16)x.z; v[3] = (bf16)x.w;
    v[4] = (bf16)y.x; v[5] = (bf16)y.y; v[6] = (bf16)y.z; v[7] = (bf16)y.w;
    *(bf16x8*)(a.dst[tid] + 8 * (size_t)off) = v;
}

// ---------------- GEMM core: C = A(M,K) @ Bt(N,K)^T + bias ; 128x128 tile, BK=32, m97 staging ----
__device__ __forceinline__ void gemm_core(const bf16* __restrict__ A, const bf16* __restrict__ Bt,
                                          const float* __restrict__ bias, void* __restrict__ out,
                                          int mode, bf16* As, bf16* Bs) {
    const int K = DM;
    int t = threadIdx.x;
    int lane = t & 63, wave = t >> 6;
    int lm = lane & 15, quad = lane >> 4;
    int m0 = blockIdx.y * 128, n0 = blockIdx.x * 128;
    int wm = (wave >> 1) * 64, wn = (wave & 1) * 64;
    f32x4 acc[4][4] = {};
    int g0 = t, g1 = t + 256;  // granule ids (row = g>>2, kq = g&3)
    const bf16* agp0 = A + (size_t)(m0 + (g0 >> 2)) * K + (g0 & 3) * 8;
    const bf16* agp1 = A + (size_t)(m0 + (g1 >> 2)) * K + (g1 & 3) * 8;
    const bf16* bgp0 = Bt + (size_t)(n0 + (g0 >> 2)) * K + (g0 & 3) * 8;
    const bf16* bgp1 = Bt + (size_t)(n0 + (g1 >> 2)) * K + (g1 & 3) * 8;
    bf16* al0 = As + wave * 512;
    bf16* al1 = As + 2048 + wave * 512;
    bf16* bl0 = Bs + wave * 512;
    bf16* bl1 = Bs + 2048 + wave * 512;
    for (int k0 = 0; k0 < K; k0 += 32) {
        gload_lds16(agp0 + k0, al0);
        gload_lds16(agp1 + k0, al1);
        gload_lds16(bgp0 + k0, bl0);
        gload_lds16(bgp1 + k0, bl1);
        __syncthreads();
        bf16x8 af[4], bfr[4];
#pragma unroll
        for (int i = 0; i < 4; ++i)
            af[i] = *(const bf16x8*)(As + (wm + i * 16 + lm) * 32 + quad * 8);
#pragma unroll
        for (int j = 0; j < 4; ++j)
            bfr[j] = *(const bf16x8*)(Bs + (wn + j * 16 + lm) * 32 + quad * 8);
#pragma unroll
        for (int i = 0; i < 4; ++i)
#pragma unroll
            for (int j = 0; j < 4; ++j)
                acc[i][j] = __builtin_amdgcn_mfma_f32_16x16x32_bf16(af[i], bfr[j], acc[i][j], 0, 0, 0);
        __syncthreads();
    }
#pragma unroll
    for (int i = 0; i < 4; ++i) {
#pragma unroll
        for (int j = 0; j < 4; ++j) {
            int col = n0 + wn + j * 16 + lm;
            float bv = bias[col];
            f32x4 v = acc[i][j];
#pragma unroll
            for (int r = 0; r < 4; ++r) {
                int row = m0 + wm + i * 16 + quad * 4 + r;
                float val = v[r] + bv;
                if (mode == 0) {
                    ((bf16*)out)[(size_t)row * DM + col] = (bf16)val;
                } else if (mode == 1) {  // V^T (B,H,DK,S)
                    int s = row >> 1, b = row & 1;
                    int h = col >> 6, dk = col & 63;
                    ((bf16*)out)[((size_t)(b * NH + h) * DKH + dk) * S_LEN + s] = (bf16)val;
                } else {
                    ((float*)out)[(size_t)row * DM + col] = val;
                }
            }
        }
    }
}

struct QKVArgs { const bf16* A[3]; const bf16* W[3]; const float* bias[3]; void* out[3]; int mode[3]; };

__global__ __launch_bounds__(256) void gemm_qkv(QKVArgs args) {
    __shared__ __align__(16) bf16 As[128 * 32];
    __shared__ __align__(16) bf16 Bs[128 * 32];
    int z = blockIdx.z;
    gemm_core(args.A[z], args.W[z], args.bias[z], args.out[z], args.mode[z], As, Bs);
}

__global__ __launch_bounds__(256) void gemm_one(const bf16* __restrict__ A, const bf16* __restrict__ Bt,
                                                const float* __restrict__ bias, void* __restrict__ out,
                                                int mode) {
    __shared__ __align__(16) bf16 As[128 * 32];
    __shared__ __align__(16) bf16 Bs[128 * 32];
    gemm_core(A, Bt, bias, out, mode, As, Bs);
}

// ---------------- RoPE in-place (q gets 0.125*log2e folded in) ----------------
__global__ __launch_bounds__(256) void rope_kernel(bf16* __restrict__ q, bf16* __restrict__ k,
                                                   const float* __restrict__ qc, const float* __restrict__ qs,
                                                   const float* __restrict__ kc, const float* __restrict__ ks) {
    int i = blockIdx.x * 256 + threadIdx.x;
    int dk = i & 31;
    int h = (i >> 5) & 15;
    int b = (i >> 9) & 1;
    int s = i >> 10;
    size_t base = ((size_t)s * BATCH + b) * DM + h * DKH;
    int ti = s * DKH + dk;
    const float qscale = 0.125f * 1.44269504088896f;
    float c1 = qc[ti], s1 = qs[ti], c2 = qc[ti + 32], s2 = qs[ti + 32];
    float x1 = (float)q[base + dk], x2 = (float)q[base + dk + 32];
    q[base + dk]      = (bf16)((x1 * c1 - x2 * s1) * qscale);
    q[base + dk + 32] = (bf16)((x2 * c2 + x1 * s2) * qscale);
    float kc1 = kc[ti], ks1 = ks[ti], kc2 = kc[ti + 32], ks2 = ks[ti + 32];
    float y1 = (float)k[base + dk], y2 = (float)k[base + dk + 32];
    k[base + dk]      = (bf16)(y1 * kc1 - y2 * ks1);
    k[base + dk + 32] = (bf16)(y2 * kc2 + y1 * ks2);
}

// ---------------- Flash attention v2: transposed scores S^T = K.Q^T ----------------
// Block: 128 q rows (4 waves x 32 q), KV tile 64 staged in LDS via global_load_lds.
// S^T C-layout: col = q = lm (per-lane softmax state), row = kv = quad*4+r.
__global__ __launch_bounds__(256, 2) void flash_kernel(const bf16* __restrict__ qp, const bf16* __restrict__ kp,
                                                       const bf16* __restrict__ vT, bf16* __restrict__ ctx) {
    int qt = 15 - blockIdx.x;  // longest blocks dispatch first (causal balance)
    int bh = blockIdx.y;
    int b = bh >> 4, h = bh & 15;
    int t = threadIdx.x, lane = t & 63, wave = t >> 6;
    int lm = lane & 15, quad = lane >> 4;
    __shared__ __align__(16) bf16 Ks[2 * 64 * 32];  // [dk_half][kv][32]
    __shared__ __align__(16) bf16 Vs[2 * 64 * 32];  // [kv_half][dk][32]
    __shared__ __align__(16) uint32_t Pb[4][16 * 36];  // per-wave P, row stride 36 u32
    uint32_t* pw = &Pb[wave][0];
    const int q0w = qt * 128 + wave * 32;

    // Q fragments (B-operand: lane lm = q, k = dk)
    bf16x8 aq[2][2];
#pragma unroll
    for (int u = 0; u < 2; ++u) {
        const bf16* qrow = qp + ((size_t)(q0w + u * 16 + lm) * BATCH + b) * DM + h * DKH;
        aq[u][0] = *(const bf16x8*)(qrow + quad * 8);
        aq[u][1] = *(const bf16x8*)(qrow + 32 + quad * 8);
    }
    f32x4 o[2][4] = {};
    float m_u[2] = {-1e30f, -1e30f};
    float l_u[2] = {0.f, 0.f};

    // staging granule decode: g = issue*256 + t
    int gA = t, gB = t + 256;
    int aKv = (gA & 255) >> 2, aDq = ((gA >> 8) << 2) + (gA & 3);
    int bKv = (gB & 255) >> 2, bDq = ((gB >> 8) << 2) + (gB & 3);
    const bf16* kgp0 = kp + ((size_t)aKv * BATCH + b) * DM + h * DKH + aDq * 8;
    const bf16* kgp1 = kp + ((size_t)bKv * BATCH + b) * DM + h * DKH + bDq * 8;
    const bf16* vgp0 = vT + ((size_t)bh * DKH + aKv) * S_LEN + aDq * 8;  // same decode: dk=aKv, kvq=aDq
    const bf16* vgp1 = vT + ((size_t)bh * DKH + bKv) * S_LEN + bDq * 8;
    bf16* kl0 = Ks + wave * 512;
    bf16* kl1 = Ks + 2048 + wave * 512;
    bf16* vl0 = Vs + wave * 512;
    bf16* vl1 = Vs + 2048 + wave * 512;

    const int kv_end = qt * 128 + 128;
    const int wave_qmax = q0w + 31;
    const size_t kstep = (size_t)BATCH * DM;

    for (int kv0 = 0; kv0 < kv_end; kv0 += 64) {
        gload_lds16(kgp0 + (size_t)kv0 * kstep, kl0);
        gload_lds16(kgp1 + (size_t)kv0 * kstep, kl1);
        gload_lds16(vgp0 + kv0, vl0);
        gload_lds16(vgp1 + kv0, vl1);
        __syncthreads();
        if (kv0 <= wave_qmax) {  // wave-uniform causal skip
            bf16x8 kf[4][2], vf[4][2];
#pragma unroll
            for (int nt = 0; nt < 4; ++nt) {
                kf[nt][0] = *(const bf16x8*)(Ks + (nt * 16 + lm) * 32 + quad * 8);
                kf[nt][1] = *(const bf16x8*)(Ks + 2048 + (nt * 16 + lm) * 32 + quad * 8);
            }
#pragma unroll
            for (int dt = 0; dt < 4; ++dt) {
                vf[dt][0] = *(const bf16x8*)(Vs + (dt * 16 + lm) * 32 + quad * 8);
                vf[dt][1] = *(const bf16x8*)(Vs + 2048 + (dt * 16 + lm) * 32 + quad * 8);
            }
            const f32x4 zero = {0.f, 0.f, 0.f, 0.f};
            f32x4 sc[2][4];
#pragma unroll
            for (int u = 0; u < 2; ++u)
#pragma unroll
                for (int nt = 0; nt < 4; ++nt) {
                    sc[u][nt] = __builtin_amdgcn_mfma_f32_16x16x32_bf16(kf[nt][0], aq[u][0], zero, 0, 0, 0);
                    sc[u][nt] = __builtin_amdgcn_mfma_f32_16x16x32_bf16(kf[nt][1], aq[u][1], sc[u][nt], 0, 0, 0);
                }
            // causal mask (only near diagonal; wave-uniform test per u)
#pragma unroll
            for (int u = 0; u < 2; ++u) {
                int qu0 = q0w + u * 16;
                if (kv0 + 63 > qu0) {
#pragma unroll
                    for (int nt = 0; nt < 4; ++nt)
#pragma unroll
                        for (int r = 0; r < 4; ++r) {
                            int kvg = kv0 + nt * 16 + quad * 4 + r;
                            if (kvg > qu0 + lm) sc[u][nt][r] = -1e30f;
                        }
                }
            }
#pragma unroll
            for (int u = 0; u < 2; ++u) {
                float mx = sc[u][0][0];
#pragma unroll
                for (int nt = 0; nt < 4; ++nt)
#pragma unroll
                    for (int r = 0; r < 4; ++r) mx = fmaxf(mx, sc[u][nt][r]);
                mx = fmaxf(mx, __shfl_xor(mx, 16, 64));
                mx = fmaxf(mx, __shfl_xor(mx, 32, 64));
                float mn = fmaxf(m_u[u], mx);
                float al = exp2f(m_u[u] - mn);
                m_u[u] = mn;
                float rs = 0.f;
                uint32_t pk[8];
#pragma unroll
                for (int nt = 0; nt < 4; ++nt)
#pragma unroll
                    for (int rp = 0; rp < 2; ++rp) {
                        float p0 = exp2f(sc[u][nt][2 * rp] - mn);
                        float p1 = exp2f(sc[u][nt][2 * rp + 1] - mn);
                        rs += p0 + p1;
                        pk[nt * 2 + rp] = pack2(p0, p1);
                    }
                rs += __shfl_xor(rs, 16, 64);
                rs += __shfl_xor(rs, 32, 64);
                l_u[u] = l_u[u] * al + rs;
#pragma unroll
                for (int dt = 0; dt < 4; ++dt) o[u][dt] *= al;
                // P -> B-frag layout via per-wave LDS: row q=lm, u32 col = kv pair
#pragma unroll
                for (int nt = 0; nt < 4; ++nt)
#pragma unroll
                    for (int rp = 0; rp < 2; ++rp)
                        pw[lm * 36 + nt * 8 + quad * 2 + rp] = pk[nt * 2 + rp];
                __builtin_amdgcn_wave_barrier();
                const uint32_t* pr = pw + lm * 36;
                bf16x8 pf0 = *(const bf16x8*)(pr + quad * 4);
                bf16x8 pf1 = *(const bf16x8*)(pr + 16 + quad * 4);
#pragma unroll
                for (int dt = 0; dt < 4; ++dt) {
                    o[u][dt] = __builtin_amdgcn_mfma_f32_16x16x32_bf16(vf[dt][0], pf0, o[u][dt], 0, 0, 0);
                    o[u][dt] = __builtin_amdgcn_mfma_f32_16x16x32_bf16(vf[dt][1], pf1, o[u][dt], 0, 0, 0);
                }
                __builtin_amdgcn_wave_barrier();
            }
        }
        __syncthreads();
    }
    // epilogue: O^T C-layout -> ctx row-major; pack 4 bf16 (contiguous dk) per store
#pragma unroll
    for (int u = 0; u < 2; ++u) {
        float linv = 1.f / l_u[u];
        int qg = q0w + u * 16 + lm;
        bf16* crow = ctx + ((size_t)qg * BATCH + b) * DM + h * DKH;
#pragma unroll
        for (int dt = 0; dt < 4; ++dt) {
            bf16x4 v;
#pragma unroll
            for (int r = 0; r < 4; ++r) v[r] = (bf16)(o[u][dt][r] * linv);
            *(bf16x4*)(crow + dt * 16 + quad * 4) = v;
        }
    }
}

extern "C" void kernel_launch(void* const* d_in, const int* in_sizes, int n_in,
                              void* d_out, int out_size, void* d_ws, size_t ws_size,
                              hipStream_t stream) {
    const float* Q    = (const float*)d_in[0];
    const float* K    = (const float*)d_in[1];
    const float* V    = (const float*)d_in[2];
    const float* Wq   = (const float*)d_in[3];
    const float* bq   = (const float*)d_in[4];
    const float* Wk   = (const float*)d_in[5];
    const float* bk   = (const float*)d_in[6];
    const float* Wv   = (const float*)d_in[7];
    const float* bv   = (const float*)d_in[8];
    const float* Wo   = (const float*)d_in[9];
    const float* bo   = (const float*)d_in[10];
    const float* qcos = (const float*)d_in[11];
    const float* qsin = (const float*)d_in[12];
    const float* kcos = (const float*)d_in[13];
    const float* ksin = (const float*)d_in[14];
    // d_in[15] = mask: deterministic causal triu(k=1); applied analytically.

    char* ws = (char*)d_ws;
    const size_t SZ_ACT = (size_t)MTOT * DM * sizeof(bf16);  // 8 MiB
    const size_t SZ_W   = (size_t)DM * DM * sizeof(bf16);    // 2 MiB
    bf16* qb  = (bf16*)ws; ws += SZ_ACT;
    bf16* kb  = (bf16*)ws; ws += SZ_ACT;
    bf16* vb  = (bf16*)ws; ws += SZ_ACT;
    bf16* wqb = (bf16*)ws; ws += SZ_W;
    bf16* wkb = (bf16*)ws; ws += SZ_W;
    bf16* wvb = (bf16*)ws; ws += SZ_W;
    bf16* wob = (bf16*)ws; ws += SZ_W;
    bf16* qpr = (bf16*)ws; ws += SZ_ACT;
    bf16* kpr = (bf16*)ws; ws += SZ_ACT;
    bf16* vTp = (bf16*)ws; ws += SZ_ACT;
    bf16* ctx = (bf16*)ws; ws += SZ_ACT;

    ConvArgs ca;
    ca.src[0] = Q;  ca.dst[0] = qb;
    ca.src[1] = K;  ca.dst[1] = kb;
    ca.src[2] = V;  ca.dst[2] = vb;
    ca.src[3] = Wq; ca.dst[3] = wqb;
    ca.src[4] = Wk; ca.dst[4] = wkb;
    ca.src[5] = Wv; ca.dst[5] = wvb;
    ca.src[6] = Wo; ca.dst[6] = wob;
    convert_all<<<8192, 256, 0, stream>>>(ca);

    QKVArgs qa;
    qa.A[0] = qb; qa.W[0] = wqb; qa.bias[0] = bq; qa.out[0] = qpr; qa.mode[0] = 0;
    qa.A[1] = kb; qa.W[1] = wkb; qa.bias[1] = bk; qa.out[1] = kpr; qa.mode[1] = 0;
    qa.A[2] = vb; qa.W[2] = wvb; qa.bias[2] = bv; qa.out[2] = vTp; qa.mode[2] = 1;
    gemm_qkv<<<dim3(DM / 128, MTOT / 128, 3), 256, 0, stream>>>(qa);

    rope_kernel<<<(S_LEN * BATCH * NH * 32) / 256, 256, 0, stream>>>(qpr, kpr, qcos, qsin, kcos, ksin);

    flash_kernel<<<dim3(S_LEN / 128, BATCH * NH), 256, 0, stream>>>(qpr, kpr, vTp, ctx);

    gemm_one<<<dim3(DM / 128, MTOT / 128), 256, 0, stream>>>(ctx, wob, bo, (float*)d_out, 2);
}